// Round 2
// baseline (1742.661 us; speedup 1.0000x reference)
//
#include <hip/hip_runtime.h>
#include <cstdint>
#include <cstddef>

#define TSTEPS 500
#define BATCH  64
#define FEAT   256
#define HID    512
#define OUTD   128
#define ZROW   512   // index of the all-zero padding row in wrecT/woutT

// ---------------- workspace layout (bytes) ----------------
#define XPROJ_OFF   ((size_t)0)
#define XPROJ_BYTES ((size_t)TSTEPS*BATCH*HID*4)          // 65,536,000
#define WRECT_OFF   (XPROJ_OFF + XPROJ_BYTES)
#define WRECT_BYTES ((size_t)(HID+1)*HID*4)               // 513 rows x 512
#define WOUTT_OFF   (WRECT_OFF + WRECT_BYTES)
#define WOUTT_BYTES ((size_t)(HID+1)*OUTD*4)              // 513 rows x 128
#define LISTS_OFF   (WOUTT_OFF + WOUTT_BYTES)
#define LISTS_BYTES ((size_t)TSTEPS*BATCH*HID*2)          // 32,768,000
#define CNTS_OFF    (LISTS_OFF + LISTS_BYTES)
#define CNTS_BYTES  ((size_t)TSTEPS*BATCH*4)              // 128,000

// ---------------- prep: transpose w_rec (512x512) and w_out (128x512) + zero rows ----------------
__global__ __launch_bounds__(256) void prep_kernel(const float* __restrict__ w_rec,
                                                   const float* __restrict__ w_out,
                                                   float* __restrict__ w_recT,
                                                   float* __restrict__ w_outT) {
    __shared__ float tile[32][33];
    int bid = blockIdx.x;
    const int tid = threadIdx.x;

    if (bid == 320) {                 // zero padding rows
        for (int i = tid; i < HID; i += 256) w_recT[(size_t)ZROW * HID + i] = 0.f;
        if (tid < OUTD) w_outT[(size_t)ZROW * OUTD + tid] = 0.f;
        return;
    }

    const float* src;
    float* dst;
    int scols, srows, tr, tc;
    if (bid < 256) {                  // w_rec: 512x512 -> 16x16 tiles of 32
        src = w_rec; dst = w_recT; srows = 512; scols = 512;
        tr = bid >> 4; tc = bid & 15;
    } else {                          // w_out: 128x512 -> 4x16 tiles of 32
        bid -= 256;
        src = w_out; dst = w_outT; srows = 128; scols = 512;
        tr = bid >> 4; tc = bid & 15;
    }
    const int c = tid & 31;
    const int r0 = tid >> 5;          // 0..7
#pragma unroll
    for (int p = 0; p < 4; ++p) {
        int r = p * 8 + r0;
        tile[r][c] = src[(size_t)(tr * 32 + r) * scols + tc * 32 + c];
    }
    __syncthreads();
#pragma unroll
    for (int p = 0; p < 4; ++p) {
        int r = p * 8 + r0;
        dst[(size_t)(tc * 32 + r) * srows + tr * 32 + c] = tile[c][r];
    }
}

// ---------------- x_proj GEMM: [32000x256] * [512x256]^T -> [32000x512] fp32 ----------------
__global__ __launch_bounds__(256) void xproj_kernel(const float* __restrict__ x,
                                                    const float* __restrict__ w_in,
                                                    float* __restrict__ xp) {
    __shared__ float At[32][132];
    __shared__ float Bt[32][132];
    const int tid = threadIdx.x;
    const int bm = blockIdx.x % 250;
    const int bn = blockIdx.x / 250;
    const int m0 = bm * 128, n0 = bn * 128;
    const int tx = tid & 15, ty = tid >> 4;
    const int lr = tid >> 3;
    const int lc = (tid & 7) << 2;

    float acc[8][8];
#pragma unroll
    for (int i = 0; i < 8; ++i)
#pragma unroll
        for (int j = 0; j < 8; ++j) acc[i][j] = 0.f;

    for (int k0 = 0; k0 < FEAT; k0 += 32) {
#pragma unroll
        for (int rr = 0; rr < 128; rr += 32) {
            float4 av = *reinterpret_cast<const float4*>(x + (size_t)(m0 + lr + rr) * FEAT + k0 + lc);
            At[lc + 0][lr + rr] = av.x; At[lc + 1][lr + rr] = av.y;
            At[lc + 2][lr + rr] = av.z; At[lc + 3][lr + rr] = av.w;
            float4 bv = *reinterpret_cast<const float4*>(w_in + (size_t)(n0 + lr + rr) * FEAT + k0 + lc);
            Bt[lc + 0][lr + rr] = bv.x; Bt[lc + 1][lr + rr] = bv.y;
            Bt[lc + 2][lr + rr] = bv.z; Bt[lc + 3][lr + rr] = bv.w;
        }
        __syncthreads();
#pragma unroll
        for (int kk = 0; kk < 32; ++kk) {
            float a[8], bb[8];
            *reinterpret_cast<float4*>(&a[0]) = *reinterpret_cast<const float4*>(&At[kk][ty * 8]);
            *reinterpret_cast<float4*>(&a[4]) = *reinterpret_cast<const float4*>(&At[kk][ty * 8 + 4]);
            *reinterpret_cast<float4*>(&bb[0]) = *reinterpret_cast<const float4*>(&Bt[kk][tx * 8]);
            *reinterpret_cast<float4*>(&bb[4]) = *reinterpret_cast<const float4*>(&Bt[kk][tx * 8 + 4]);
#pragma unroll
            for (int i = 0; i < 8; ++i)
#pragma unroll
                for (int j = 0; j < 8; ++j)
                    acc[i][j] = fmaf(a[i], bb[j], acc[i][j]);
        }
        __syncthreads();
    }
#pragma unroll
    for (int i = 0; i < 8; ++i) {
        float* dst = xp + (size_t)(m0 + ty * 8 + i) * HID + n0 + tx * 8;
        *reinterpret_cast<float4*>(dst)     = make_float4(acc[i][0], acc[i][1], acc[i][2], acc[i][3]);
        *reinterpret_cast<float4*>(dst + 4) = make_float4(acc[i][4], acc[i][5], acc[i][6], acc[i][7]);
    }
}

// ---------------- recurrent LIF-AdEx scan: one block (256 thr) per batch element ----------------
// Thread tid owns hidden columns h0=2*tid, h1=2*tid+1.
__global__ __launch_bounds__(256, 1) void scan_kernel(const float* __restrict__ xproj,
                                                      const float* __restrict__ wrecT,  // [513][512]
                                                      unsigned short* __restrict__ glists,
                                                      int* __restrict__ gcnts,
                                                      float* __restrict__ st_out) {
    const int b = blockIdx.x;
    const int tid = threadIdx.x;
    const int lane = tid & 63;
    const int wv = tid >> 6;                       // 0..3
    __shared__ unsigned long long zw0[4], zw1[4];
    __shared__ unsigned short slist[2][HID];

    float v0=0.f,v1=0.f,i0=0.f,i1=0.f,a0=0.f,a1=0.f,zf0=0.f,zf1=0.f;
    int cnt = 0;
    int pb = 0;                                    // buffer written this step; read pb^1
    const unsigned long long lm = (1ULL << lane) - 1ULL;

    const float* xpp = xproj + (size_t)b * HID + 2 * tid;
    float2 xpn = *reinterpret_cast<const float2*>(xpp);          // t = 0

    for (int t = 0; t < TSTEPS; ++t) {
        float2 xp = xpn;
        if (t + 1 < TSTEPS)
            xpn = *reinterpret_cast<const float2*>(xpp + (size_t)(t + 1) * BATCH * HID);

        // ---- recurrent input: sum of wrecT rows over previous spike list (64-deep MLP) ----
        float r0 = 0.f, r1 = 0.f;
        const unsigned short* lst = slist[pb ^ 1];
        for (int s0 = 0; s0 < cnt; s0 += 64) {
            float2 f[64];
#pragma unroll
            for (int q = 0; q < 16; ++q) {
                ushort4 u = *reinterpret_cast<const ushort4*>(&lst[s0 + 4 * q]);
                f[4*q+0] = *reinterpret_cast<const float2*>(wrecT + (size_t)u.x * HID + 2 * tid);
                f[4*q+1] = *reinterpret_cast<const float2*>(wrecT + (size_t)u.y * HID + 2 * tid);
                f[4*q+2] = *reinterpret_cast<const float2*>(wrecT + (size_t)u.z * HID + 2 * tid);
                f[4*q+3] = *reinterpret_cast<const float2*>(wrecT + (size_t)u.w * HID + 2 * tid);
            }
            float A0=0.f,A1=0.f,B0=0.f,B1=0.f,C0=0.f,C1=0.f,D0=0.f,D1=0.f;
#pragma unroll
            for (int j = 0; j < 64; j += 4) {
                A0 += f[j+0].x; A1 += f[j+0].y;
                B0 += f[j+1].x; B1 += f[j+1].y;
                C0 += f[j+2].x; C1 += f[j+2].y;
                D0 += f[j+3].x; D1 += f[j+3].y;
            }
            r0 += (A0 + B0) + (C0 + D0);
            r1 += (A1 + B1) + (C1 + D1);
        }

        // ---- LIF-AdEx element-wise update (reference expression forms) ----
        float vd0 = v0 + 0.1f * ((((0.f - v0) + 0.5f * expf((v0 - 1.f) * 2.f)) + i0) - a0);
        float vd1 = v1 + 0.1f * ((((0.f - v1) + 0.5f * expf((v1 - 1.f) * 2.f)) + i1) - a1);
        float id0 = i0 - 0.2f * i0;
        float id1 = i1 - 0.2f * i1;
        float aD0 = a0 + 0.002f * (4.f * v0 - a0);
        float aD1 = a1 + 0.002f * (4.f * v1 - a1);
        bool z0 = (vd0 - 1.f) > 0.f;
        bool z1 = (vd1 - 1.f) > 0.f;
        v0 = z0 ? 0.f : vd0;            v1 = z1 ? 0.f : vd1;
        i0 = id0 + xp.x + r0;           i1 = id1 + xp.y + r1;
        a0 = aD0 + (z0 ? 0.02f : 0.f);  a1 = aD1 + (z1 ? 0.02f : 0.f);
        zf0 = z0 ? 1.f : 0.f;           zf1 = z1 ? 1.f : 0.f;

        // ---- build next spike list (double-buffered, 2 barriers/step) ----
        unsigned long long m0 = __ballot(z0);
        unsigned long long m1 = __ballot(z1);
        if (lane == 0) { zw0[wv] = m0; zw1[wv] = m1; }
        __syncthreads();
        int base0 = 0, off0 = 0, off1 = 0, tot = 0;
#pragma unroll
        for (int w = 0; w < 4; ++w) {
            int p0 = __popcll(zw0[w]), p1 = __popcll(zw1[w]);
            base0 += p0;
            if (w < wv) { off0 += p0; off1 += p1; }
            tot += p0 + p1;
        }
        unsigned short* nl = slist[pb];
        unsigned short* grow = glists + ((size_t)t * BATCH + b) * HID;
        if (z0) {
            int p = off0 + __popcll(m0 & lm);
            nl[p] = (unsigned short)(2 * tid);  grow[p] = (unsigned short)(2 * tid);
        }
        if (z1) {
            int p = base0 + off1 + __popcll(m1 & lm);
            nl[p] = (unsigned short)(2 * tid + 1);  grow[p] = (unsigned short)(2 * tid + 1);
        }
        int pad = (tot + 63) & ~63;
        for (int ii = tid; ii < pad; ii += 256)
            if (ii >= tot) { nl[ii] = ZROW; grow[ii] = ZROW; }
        if (tid == 0) gcnts[t * BATCH + b] = tot;
        __syncthreads();
        cnt = tot;
        pb ^= 1;
    }

    // final states: z, v, i, a  each [64][512]
    const size_t base = (size_t)b * HID + 2 * tid;
    *reinterpret_cast<float2*>(st_out + 0 * (size_t)BATCH * HID + base) = make_float2(zf0, zf1);
    *reinterpret_cast<float2*>(st_out + 1 * (size_t)BATCH * HID + base) = make_float2(v0, v1);
    *reinterpret_cast<float2*>(st_out + 2 * (size_t)BATCH * HID + base) = make_float2(i0, i1);
    *reinterpret_cast<float2*>(st_out + 3 * (size_t)BATCH * HID + base) = make_float2(a0, a1);
}

// ---------------- output projection + exponential filter ----------------
// 8 t-chunks x 64 batch = 512 blocks; 64-step halo (0.7769^64 ~ 1e-7) decouples chunks.
__global__ __launch_bounds__(128, 1) void out_kernel(const unsigned short* __restrict__ lists,
                                                     const int* __restrict__ cnts,
                                                     const float* __restrict__ woutT,  // [513][128]
                                                     const float* __restrict__ b_out,
                                                     float* __restrict__ out) {
    const int bid = blockIdx.x;
    const int b = bid & 63;
    const int chunk = bid >> 6;          // 0..7
    const int o = threadIdx.x;
    const int t0 = chunk * 63;
    const int tstart = (t0 >= 64) ? (t0 - 64) : 0;
    int tend = t0 + 63; if (tend > TSTEPS) tend = TSTEPS;
    const float bo = b_out[o];
    const float cf = 0.2231435511314f;
    float y = 0.f;
    for (int t = tstart; t < tend; ++t) {
        const unsigned short* lp = lists + ((size_t)t * BATCH + b) * HID;
        const int cnt = cnts[t * BATCH + b];
        float lin = bo;
        for (int s0 = 0; s0 < cnt; s0 += 64) {
            float f[64];
#pragma unroll
            for (int q = 0; q < 16; ++q) {
                ushort4 u = *reinterpret_cast<const ushort4*>(lp + s0 + 4 * q);
                f[4*q+0] = woutT[(size_t)u.x * OUTD + o];
                f[4*q+1] = woutT[(size_t)u.y * OUTD + o];
                f[4*q+2] = woutT[(size_t)u.z * OUTD + o];
                f[4*q+3] = woutT[(size_t)u.w * OUTD + o];
            }
            float A=0.f,B=0.f,C=0.f,D=0.f;
#pragma unroll
            for (int j = 0; j < 64; j += 4) {
                A += f[j+0]; B += f[j+1]; C += f[j+2]; D += f[j+3];
            }
            lin += (A + B) + (C + D);
        }
        y = y + cf * (lin - y);
        if (t >= t0) out[((size_t)t * BATCH + b) * OUTD + o] = y;
    }
}

// ---------------- launcher ----------------
extern "C" void kernel_launch(void* const* d_in, const int* in_sizes, int n_in,
                              void* d_out, int out_size, void* d_ws, size_t ws_size,
                              hipStream_t stream) {
    const float* x     = (const float*)d_in[0];
    const float* w_in  = (const float*)d_in[1];
    const float* w_rec = (const float*)d_in[2];
    const float* w_out = (const float*)d_in[3];
    const float* b_out = (const float*)d_in[4];
    float* out = (float*)d_out;

    char* ws = (char*)d_ws;
    float* xproj          = (float*)(ws + XPROJ_OFF);
    float* wrecT          = (float*)(ws + WRECT_OFF);
    float* woutT          = (float*)(ws + WOUTT_OFF);
    unsigned short* lists = (unsigned short*)(ws + LISTS_OFF);
    int* cnts             = (int*)(ws + CNTS_OFF);
    float* st_out = out + (size_t)TSTEPS * BATCH * OUTD;

    prep_kernel<<<321, 256, 0, stream>>>(w_rec, w_out, wrecT, woutT);
    xproj_kernel<<<1000, 256, 0, stream>>>(x, w_in, xproj);
    scan_kernel<<<64, 256, 0, stream>>>(xproj, wrecT, lists, cnts, st_out);
    out_kernel<<<512, 128, 0, stream>>>(lists, cnts, woutT, b_out, out);
}

// Round 4
// 879.973 us; speedup vs baseline: 1.9804x; 1.9804x over previous
//
#include <hip/hip_runtime.h>
#include <cstdint>
#include <cstddef>

#define TSTEPS 500
#define BATCH  64
#define FEAT   256
#define HID    512
#define OUTD   128
#define ZROW   512   // all-zero padding row in wrecT/woutT

// ---------------- workspace layout (bytes) ----------------
#define XPROJ_OFF   ((size_t)0)
#define XPROJ_BYTES ((size_t)TSTEPS*BATCH*HID*4)
#define WRECT_OFF   (XPROJ_OFF + XPROJ_BYTES)
#define WRECT_BYTES ((size_t)(HID+1)*HID*4)
#define WOUTT_OFF   (WRECT_OFF + WRECT_BYTES)
#define WOUTT_BYTES ((size_t)(HID+1)*OUTD*4)
#define LISTS_OFF   (WOUTT_OFF + WOUTT_BYTES)
#define LISTS_BYTES ((size_t)TSTEPS*BATCH*HID*2)
#define CNTS_OFF    (LISTS_OFF + LISTS_BYTES)
#define CNTS_BYTES  ((size_t)TSTEPS*BATCH*4)

// ---------------- prep: transposes + zero pad rows ----------------
__global__ __launch_bounds__(256) void prep_kernel(const float* __restrict__ w_rec,
                                                   const float* __restrict__ w_out,
                                                   float* __restrict__ w_recT,
                                                   float* __restrict__ w_outT) {
    __shared__ float tile[32][33];
    int bid = blockIdx.x;
    const int tid = threadIdx.x;

    if (bid == 320) {                 // zero padding rows
        for (int i = tid; i < HID; i += 256) w_recT[(size_t)ZROW * HID + i] = 0.f;
        if (tid < OUTD) w_outT[(size_t)ZROW * OUTD + tid] = 0.f;
        return;
    }

    const float* src;
    float* dst;
    int scols, srows, tr, tc;
    if (bid < 256) {                  // w_rec: 512x512
        src = w_rec; dst = w_recT; srows = 512; scols = 512;
        tr = bid >> 4; tc = bid & 15;
    } else {                          // w_out: 128x512
        bid -= 256;
        src = w_out; dst = w_outT; srows = 128; scols = 512;
        tr = bid >> 4; tc = bid & 15;
    }
    const int c = tid & 31;
    const int r0 = tid >> 5;
#pragma unroll
    for (int p = 0; p < 4; ++p) {
        int r = p * 8 + r0;
        tile[r][c] = src[(size_t)(tr * 32 + r) * scols + tc * 32 + c];
    }
    __syncthreads();
#pragma unroll
    for (int p = 0; p < 4; ++p) {
        int r = p * 8 + r0;
        dst[(size_t)(tc * 32 + r) * srows + tr * 32 + c] = tile[c][r];
    }
}

// ---------------- x_proj GEMM: [32000x256] * [512x256]^T -> [32000x512] fp32 ----------------
__global__ __launch_bounds__(256) void xproj_kernel(const float* __restrict__ x,
                                                    const float* __restrict__ w_in,
                                                    float* __restrict__ xp) {
    __shared__ float At[32][132];
    __shared__ float Bt[32][132];
    const int tid = threadIdx.x;
    const int bm = blockIdx.x % 250;
    const int bn = blockIdx.x / 250;
    const int m0 = bm * 128, n0 = bn * 128;
    const int tx = tid & 15, ty = tid >> 4;
    const int lr = tid >> 3;
    const int lc = (tid & 7) << 2;

    float acc[8][8];
#pragma unroll
    for (int i = 0; i < 8; ++i)
#pragma unroll
        for (int j = 0; j < 8; ++j) acc[i][j] = 0.f;

    for (int k0 = 0; k0 < FEAT; k0 += 32) {
#pragma unroll
        for (int rr = 0; rr < 128; rr += 32) {
            float4 av = *reinterpret_cast<const float4*>(x + (size_t)(m0 + lr + rr) * FEAT + k0 + lc);
            At[lc + 0][lr + rr] = av.x; At[lc + 1][lr + rr] = av.y;
            At[lc + 2][lr + rr] = av.z; At[lc + 3][lr + rr] = av.w;
            float4 bv = *reinterpret_cast<const float4*>(w_in + (size_t)(n0 + lr + rr) * FEAT + k0 + lc);
            Bt[lc + 0][lr + rr] = bv.x; Bt[lc + 1][lr + rr] = bv.y;
            Bt[lc + 2][lr + rr] = bv.z; Bt[lc + 3][lr + rr] = bv.w;
        }
        __syncthreads();
#pragma unroll
        for (int kk = 0; kk < 32; ++kk) {
            float a[8], bb[8];
            *reinterpret_cast<float4*>(&a[0]) = *reinterpret_cast<const float4*>(&At[kk][ty * 8]);
            *reinterpret_cast<float4*>(&a[4]) = *reinterpret_cast<const float4*>(&At[kk][ty * 8 + 4]);
            *reinterpret_cast<float4*>(&bb[0]) = *reinterpret_cast<const float4*>(&Bt[kk][tx * 8]);
            *reinterpret_cast<float4*>(&bb[4]) = *reinterpret_cast<const float4*>(&Bt[kk][tx * 8 + 4]);
#pragma unroll
            for (int i = 0; i < 8; ++i)
#pragma unroll
                for (int j = 0; j < 8; ++j)
                    acc[i][j] = fmaf(a[i], bb[j], acc[i][j]);
        }
        __syncthreads();
    }
#pragma unroll
    for (int i = 0; i < 8; ++i) {
        float* dst = xp + (size_t)(m0 + ty * 8 + i) * HID + n0 + tx * 8;
        *reinterpret_cast<float4*>(dst)     = make_float4(acc[i][0], acc[i][1], acc[i][2], acc[i][3]);
        *reinterpret_cast<float4*>(dst + 4) = make_float4(acc[i][4], acc[i][5], acc[i][6], acc[i][7]);
    }
}

// ---------------- recurrent LIF-AdEx scan: one block (512 thr) per batch element ----------------
// LDS spike list holds BYTE OFFSETS into wrecT (h<<11); padded to x32 with ZROW.
__global__ __launch_bounds__(512, 1) void scan_kernel(const float* __restrict__ xproj,
                                                      const float* __restrict__ wrecT,  // [513][512]
                                                      unsigned short* __restrict__ glists,
                                                      int* __restrict__ gcnts,
                                                      float* __restrict__ st_out) {
    const int b = blockIdx.x;
    const int tid = threadIdx.x;           // h
    const int lane = tid & 63;
    const int wvi = tid >> 6;              // 0..7
    __shared__ unsigned long long zw[8];
    __shared__ int ilist[2][HID];

    float v = 0.f, cur = 0.f, ad = 0.f, zf = 0.f;
    int cntp = 0, rb = 0;
    const unsigned long long lm = (1ULL << lane) - 1ULL;
    const unsigned tid4 = (unsigned)tid << 2;
    const char* wbase = (const char*)wrecT;

    const float* xpp = xproj + (size_t)b * HID + tid;
    float xpn = xpp[0];

    for (int t = 0; t < TSTEPS; ++t) {
        const float xp = xpn;
        if (t + 1 < TSTEPS) xpn = xpp[(size_t)(t + 1) * BATCH * HID];

        // ---- recurrent gather: 32 loads in flight per chunk ----
        float r = 0.f;
        const int* lst = ilist[rb];
        for (int s0 = 0; s0 < cntp; s0 += 32) {
            int4 w[8];
#pragma unroll
            for (int q = 0; q < 8; ++q) w[q] = *reinterpret_cast<const int4*>(lst + s0 + 4 * q);
            float f[32];
#pragma unroll
            for (int q = 0; q < 8; ++q) {
                f[4*q+0] = *reinterpret_cast<const float*>(wbase + (unsigned)((unsigned)w[q].x + tid4));
                f[4*q+1] = *reinterpret_cast<const float*>(wbase + (unsigned)((unsigned)w[q].y + tid4));
                f[4*q+2] = *reinterpret_cast<const float*>(wbase + (unsigned)((unsigned)w[q].z + tid4));
                f[4*q+3] = *reinterpret_cast<const float*>(wbase + (unsigned)((unsigned)w[q].w + tid4));
            }
            __builtin_amdgcn_sched_barrier(0);   // keep all 32 loads issued before consumption
            float A = 0.f, B = 0.f, C = 0.f, D = 0.f;
#pragma unroll
            for (int j = 0; j < 32; j += 4) { A += f[j]; B += f[j+1]; C += f[j+2]; D += f[j+3]; }
            r += (A + B) + (C + D);
        }

        // ---- LIF-AdEx element-wise update ----
        float vd = v + 0.1f * ((((0.f - v) + 0.5f * expf((v - 1.f) * 2.f)) + cur) - ad);
        float id = cur - 0.2f * cur;
        float aD = ad + 0.002f * (4.f * v - ad);
        bool z = (vd - 1.f) > 0.f;
        v = z ? 0.f : vd;
        cur = id + xp + r;
        ad = aD + (z ? 0.02f : 0.f);
        zf = z ? 1.f : 0.f;

        // ---- build next spike list ----
        unsigned long long m = __ballot(z);
        if (lane == 0) zw[wvi] = m;
        __syncthreads();                       // A: zw visible; all gathers from ilist[rb] done
        int off = 0, tot = 0;
#pragma unroll
        for (int ww = 0; ww < 8; ++ww) {
            int p = __popcll(zw[ww]);
            if (ww < wvi) off += p;
            tot += p;
        }
        const int wb = rb ^ 1;
        if (z) ilist[wb][off + __popcll(m & lm)] = tid << 11;
        const int pad = (tot + 31) & ~31;
        if (tid >= tot && tid < pad) ilist[wb][tid] = ZROW << 11;
        __syncthreads();                       // B: ilist[wb] complete
        // export step-t spike list (off critical path; store doesn't block)
        if (tid < pad)
            glists[((size_t)t * BATCH + b) * HID + tid] =
                (unsigned short)(((unsigned)ilist[wb][tid]) >> 11);
        if (tid == 0) gcnts[t * BATCH + b] = pad;
        cntp = pad;
        rb = wb;
    }

    // final states: z, v, i, a  each [64][512]
    const size_t base = (size_t)b * HID + tid;
    st_out[0 * (size_t)BATCH * HID + base] = zf;
    st_out[1 * (size_t)BATCH * HID + base] = v;
    st_out[2 * (size_t)BATCH * HID + base] = cur;
    st_out[3 * (size_t)BATCH * HID + base] = ad;
}

// ---------------- output projection + exponential filter ----------------
// 16 t-chunks x 64 batch = 1024 blocks; 48-step halo (0.7769^48 ~ 5.5e-6).
__global__ __launch_bounds__(128) void out_kernel(const unsigned short* __restrict__ lists,
                                                  const int* __restrict__ cnts,
                                                  const float* __restrict__ woutT,  // [513][128]
                                                  const float* __restrict__ b_out,
                                                  float* __restrict__ out) {
    const int bid = blockIdx.x;
    const int b = bid & 63;
    const int chunk = bid >> 6;            // 0..15
    const int o = threadIdx.x;
    const unsigned o4 = (unsigned)o << 2;
    const int t0 = chunk * 32;
    const int tstart = (t0 >= 48) ? (t0 - 48) : 0;
    int tend = t0 + 32; if (tend > TSTEPS) tend = TSTEPS;
    const float bo = b_out[o];
    const float cf = 0.2231435511314f;
    const char* wbase = (const char*)woutT;
    float y = 0.f;
    for (int t = tstart; t < tend; ++t) {
        const int cnt = cnts[t * BATCH + b];           // padded to x32
        const unsigned short* lp = lists + ((size_t)t * BATCH + b) * HID;
        float lin = bo;
        for (int s0 = 0; s0 < cnt; s0 += 32) {
            uint4 u[4];
#pragma unroll
            for (int q = 0; q < 4; ++q) u[q] = *reinterpret_cast<const uint4*>(lp + s0 + 8 * q);
            float f[32];
#pragma unroll
            for (int q = 0; q < 4; ++q) {
                unsigned a0 = u[q].x, a1 = u[q].y, a2 = u[q].z, a3 = u[q].w;
                f[8*q+0] = *reinterpret_cast<const float*>(wbase + (((a0 & 0xffffu) << 9) + o4));
                f[8*q+1] = *reinterpret_cast<const float*>(wbase + (((a0 >> 16) << 9) + o4));
                f[8*q+2] = *reinterpret_cast<const float*>(wbase + (((a1 & 0xffffu) << 9) + o4));
                f[8*q+3] = *reinterpret_cast<const float*>(wbase + (((a1 >> 16) << 9) + o4));
                f[8*q+4] = *reinterpret_cast<const float*>(wbase + (((a2 & 0xffffu) << 9) + o4));
                f[8*q+5] = *reinterpret_cast<const float*>(wbase + (((a2 >> 16) << 9) + o4));
                f[8*q+6] = *reinterpret_cast<const float*>(wbase + (((a3 & 0xffffu) << 9) + o4));
                f[8*q+7] = *reinterpret_cast<const float*>(wbase + (((a3 >> 16) << 9) + o4));
            }
            __builtin_amdgcn_sched_barrier(0);
            float A = 0.f, Bs = 0.f, C = 0.f, D = 0.f;
#pragma unroll
            for (int j = 0; j < 32; j += 4) { A += f[j]; Bs += f[j+1]; C += f[j+2]; D += f[j+3]; }
            lin += (A + Bs) + (C + D);
        }
        y = y + cf * (lin - y);
        if (t >= t0) out[((size_t)t * BATCH + b) * OUTD + o] = y;
    }
}

// ---------------- launcher ----------------
extern "C" void kernel_launch(void* const* d_in, const int* in_sizes, int n_in,
                              void* d_out, int out_size, void* d_ws, size_t ws_size,
                              hipStream_t stream) {
    const float* x     = (const float*)d_in[0];
    const float* w_in  = (const float*)d_in[1];
    const float* w_rec = (const float*)d_in[2];
    const float* w_out = (const float*)d_in[3];
    const float* b_out = (const float*)d_in[4];
    float* out = (float*)d_out;

    char* ws = (char*)d_ws;
    float* xproj          = (float*)(ws + XPROJ_OFF);
    float* wrecT          = (float*)(ws + WRECT_OFF);
    float* woutT          = (float*)(ws + WOUTT_OFF);
    unsigned short* lists = (unsigned short*)(ws + LISTS_OFF);
    int* cnts             = (int*)(ws + CNTS_OFF);
    float* st_out = out + (size_t)TSTEPS * BATCH * OUTD;

    prep_kernel<<<321, 256, 0, stream>>>(w_rec, w_out, wrecT, woutT);
    xproj_kernel<<<1000, 256, 0, stream>>>(x, w_in, xproj);
    scan_kernel<<<64, 512, 0, stream>>>(xproj, wrecT, lists, cnts, st_out);
    out_kernel<<<1024, 128, 0, stream>>>(lists, cnts, woutT, b_out, out);
}